// Round 7
// baseline (2116.310 us; speedup 1.0000x reference)
//
#include <hip/hip_runtime.h>
#include <hip/hip_fp16.h>

// Problem: B=256, T=512, F=64, H=128  (GRU-D / BRITS-style recurrence)
// d_out (fp32): [0]=loss, [1..256]=predictions, [257..]=imputations [B,T,F]

#define NBATCH 256
#define NT 512
#define NF 64
#define NH 128
#define BPB 16                 // batch elements per block (MFMA M dimension)

// ---- workspace byte offsets ----
#define WHH_OFF   0u           // [16][512] uint4 packed f16 rows of W_hh
#define WIH_OFF   131072u      // [16][512] uint4 packed f16 rows of W_ih
#define WHR_OFF   262144u      // [16][64]  uint4 packed f16 rows of W_hr
#define WFR_OFF   278528u      // [8][64]   uint4 packed f16 rows of W_fr (diag zeroed)
#define INVMS_OFF 286720u      // f32[512]
#define ISTR_OFF  288768u      // f32[1]
#define GH_OFF    294912u      // f16 [B*T*128] gamma_h
#define AL_OFF    33849344u    // f16 [B*T*64]  alpha

typedef _Float16 f16x8 __attribute__((ext_vector_type(8)));
typedef float f32x4 __attribute__((ext_vector_type(4)));
typedef _Float16 half2_t __attribute__((ext_vector_type(2)));

__device__ __forceinline__ unsigned pack2(float a, float b) {
    __half2 h = __floats2half2_rn(a, b);
    return __builtin_bit_cast(unsigned, h);
}

__device__ __forceinline__ float dot2f(unsigned w, unsigned a, float acc) {
    float2 wf = __half22float2(__builtin_bit_cast(__half2, w));
    float2 af = __half22float2(__builtin_bit_cast(__half2, a));
    return fmaf(wf.x, af.x, fmaf(wf.y, af.y, acc));
}

__device__ __forceinline__ float sigm(float x) { return 1.f / (1.f + __expf(-x)); }
__device__ __forceinline__ float tanh_fast(float x) { return 1.f - 2.f / (__expf(2.f * x) + 1.f); }

__device__ __forceinline__ f16x8 as_h8(uint4 u) { return __builtin_bit_cast(f16x8, u); }

// A-fragment (M=16,K=32) from LDS row-major [batch][K...]: lane l supplies
// row = l&15, k = (l>>4)*8 + e (contiguous 8). A and B use the SAME k-gather,
// so any internal hardware k-permutation cancels in the contraction.
__device__ __forceinline__ f16x8 ldA(const __half* row, int lg, int q) {
    return as_h8(*(const uint4*)(row + q * 32 + lg * 8));
}

// ---------------------------------------------------------------------------
// prep_w: pack W_hh / W_ih / W_hr / W_fr(zero-diag) rows into f16x2 uint4 layout
// region = uint4[NCHUNK][ROWS]; chunk cb covers cols 8cb..8cb+7 of the row.
// ---------------------------------------------------------------------------
__global__ __launch_bounds__(256) void prep_w(const float* __restrict__ Whh,
                                              const float* __restrict__ Wih,
                                              const float* __restrict__ Whr,
                                              const float* __restrict__ Wfr,
                                              unsigned* __restrict__ wsu) {
    int o = blockIdx.x * 256 + threadIdx.x;
    float v0, v1;
    if (o < 32768) {                      // W_hh [512][128]
        int c = o & 3, r = (o >> 2) & 511, cb = o >> 11;
        int col = 8 * cb + 2 * c;
        v0 = Whh[r * 128 + col]; v1 = Whh[r * 128 + col + 1];
    } else if (o < 65536) {               // W_ih [512][128]
        int o2 = o - 32768;
        int c = o2 & 3, r = (o2 >> 2) & 511, cb = o2 >> 11;
        int col = 8 * cb + 2 * c;
        v0 = Wih[r * 128 + col]; v1 = Wih[r * 128 + col + 1];
    } else if (o < 69632) {               // W_hr [64][128]
        int o3 = o - 65536;
        int c = o3 & 3, f = (o3 >> 2) & 63, cb = o3 >> 8;
        int col = 8 * cb + 2 * c;
        v0 = Whr[f * 128 + col]; v1 = Whr[f * 128 + col + 1];
    } else if (o < 71680) {               // W_fr [64][64], zero diagonal
        int o4 = o - 69632;
        int c = o4 & 3, f = (o4 >> 2) & 63, cb = o4 >> 8;
        int col = 8 * cb + 2 * c;
        v0 = (col == f) ? 0.f : Wfr[f * 64 + col];
        v1 = (col + 1 == f) ? 0.f : Wfr[f * 64 + col + 1];
    } else {
        return;
    }
    wsu[o] = pack2(v0, v1);
}

// ---------------------------------------------------------------------------
// prep_msum: invms[t] = 1/(sum_b,f masks[b,t,f] + 1e-5); block 512 does
// inv_istr and zeroes d_out[0].
// ---------------------------------------------------------------------------
__global__ __launch_bounds__(256) void prep_msum(const float* __restrict__ masks,
                                                 const float* __restrict__ is_train,
                                                 float* __restrict__ invms,
                                                 float* __restrict__ inv_istr,
                                                 float* __restrict__ d_out0) {
    __shared__ float red[256];
    int tid = threadIdx.x;
    int t = blockIdx.x;
    if (t < NT) {
        int f = tid & 63, br = tid >> 6;
        float s = 0.f;
        for (int i = 0; i < 64; i++) {
            int b = br + i * 4;
            s += masks[((size_t)b * NT + t) * NF + f];
        }
        red[tid] = s;
        __syncthreads();
        for (int off = 128; off > 0; off >>= 1) {
            if (tid < off) red[tid] += red[tid + off];
            __syncthreads();
        }
        if (tid == 0) invms[t] = 1.f / (red[0] + 1e-5f);
    } else {
        red[tid] = is_train[tid];
        __syncthreads();
        for (int off = 128; off > 0; off >>= 1) {
            if (tid < off) red[tid] += red[tid + off];
            __syncthreads();
        }
        if (tid == 0) {
            *inv_istr = 1.f / (red[0] + 1e-5f);
            *d_out0 = 0.f;
        }
    }
}

// ---------------------------------------------------------------------------
// ga_kernel: precompute gamma_h[b,t,128] and alpha[b,t,64] (f16).
// ---------------------------------------------------------------------------
__global__ __launch_bounds__(256) void ga_kernel(const float* __restrict__ deltas,
                                                 const float* __restrict__ masks,
                                                 const float* __restrict__ Wdh,
                                                 const float* __restrict__ bdh,
                                                 const float* __restrict__ Wdx,
                                                 const float* __restrict__ bdx,
                                                 const float* __restrict__ Wwc,
                                                 const float* __restrict__ bwc,
                                                 __half* __restrict__ gh_all,
                                                 __half* __restrict__ al_all) {
    __shared__ unsigned wdhpk[32 * 128];
    __shared__ unsigned wwcpk[64 * 64];
    __shared__ float sbdh[128], sbdx[64], swdx[64], sbwc[64];
    __shared__ float dbuf[64];
    __shared__ __align__(16) unsigned dpk[32], gxpk[32], mpk2[32];
    int tid = threadIdx.x;

    for (int o = tid; o < 4096; o += 256) {
        int j = o & 127, k2 = o >> 7;
        wdhpk[o] = pack2(Wdh[j * 64 + 2 * k2], Wdh[j * 64 + 2 * k2 + 1]);
    }
    for (int o = tid; o < 4096; o += 256) {
        int f = o & 63, k2 = o >> 6;
        wwcpk[o] = pack2(Wwc[f * 128 + 2 * k2], Wwc[f * 128 + 2 * k2 + 1]);
    }
    if (tid < 128) sbdh[tid] = bdh[tid];
    if (tid < 64) {
        sbdx[tid] = bdx[tid];
        swdx[tid] = Wdx[tid * 65];
        sbwc[tid] = bwc[tid];
    }
    __syncthreads();

    for (int i = 0; i < 32; i++) {
        int p = blockIdx.x * 32 + i;
        if (tid < 32) {
            float2 dv = ((const float2*)(deltas + (size_t)p * NF))[tid];
            dbuf[2 * tid] = dv.x; dbuf[2 * tid + 1] = dv.y;
            dpk[tid] = pack2(dv.x, dv.y);
        } else if (tid < 64) {
            int q = tid - 32;
            float2 mv = ((const float2*)(masks + (size_t)p * NF))[q];
            mpk2[q] = pack2(mv.x, mv.y);
        }
        __syncthreads();
        if (tid < 64) {
            float gx = __expf(-fmaxf(dbuf[tid] * swdx[tid] + sbdx[tid], 0.f));
            float oth = __shfl_xor(gx, 1);
            if (!(tid & 1)) gxpk[tid >> 1] = pack2(gx, oth);
        }
        __syncthreads();
        if (tid < 128) {
            float a0 = sbdh[tid], a1 = 0.f;
            #pragma unroll
            for (int k8 = 0; k8 < 8; k8++) {
                uint4 dp = *(const uint4*)&dpk[4 * k8];
                a0 = dot2f(wdhpk[(4 * k8 + 0) * 128 + tid], dp.x, a0);
                a1 = dot2f(wdhpk[(4 * k8 + 1) * 128 + tid], dp.y, a1);
                a0 = dot2f(wdhpk[(4 * k8 + 2) * 128 + tid], dp.z, a0);
                a1 = dot2f(wdhpk[(4 * k8 + 3) * 128 + tid], dp.w, a1);
            }
            gh_all[(size_t)p * NH + tid] = __float2half(__expf(-fmaxf(a0 + a1, 0.f)));
        } else if (tid < 192) {
            int f = tid - 128;
            float a0 = sbwc[f], a1 = 0.f;
            #pragma unroll
            for (int k8 = 0; k8 < 8; k8++) {
                uint4 gp = *(const uint4*)&gxpk[4 * k8];
                a0 = dot2f(wwcpk[(4 * k8 + 0) * 64 + f], gp.x, a0);
                a1 = dot2f(wwcpk[(4 * k8 + 1) * 64 + f], gp.y, a1);
                a0 = dot2f(wwcpk[(4 * k8 + 2) * 64 + f], gp.z, a0);
                a1 = dot2f(wwcpk[(4 * k8 + 3) * 64 + f], gp.w, a1);
            }
            #pragma unroll
            for (int k8 = 0; k8 < 8; k8++) {
                uint4 mp = *(const uint4*)&mpk2[4 * k8];
                a0 = dot2f(wwcpk[(32 + 4 * k8 + 0) * 64 + f], mp.x, a0);
                a1 = dot2f(wwcpk[(32 + 4 * k8 + 1) * 64 + f], mp.y, a1);
                a0 = dot2f(wwcpk[(32 + 4 * k8 + 2) * 64 + f], mp.z, a0);
                a1 = dot2f(wwcpk[(32 + 4 * k8 + 3) * 64 + f], mp.w, a1);
            }
            al_all[(size_t)p * NF + f] = __float2half(a0 + a1);
        }
        __syncthreads();
    }
}

// ---------------------------------------------------------------------------
// main_kernel: 16 blocks, 512 threads, 16 batch elements per block.
// All recurrence GEMVs become MFMA GEMMs batched over M=16 batch rows:
//   gates-hh (K=128, 16 mfma/wave), m-gates (K=64, 8), cc-gates (K=64, 8);
//   waves 0-3 additionally x_h (K=128, 4) and z_h (K=64, 2) over f-tiles.
// C/D frag (m89): col=lane&15, row=(lane>>4)*4+reg -> pointwise is lane-local
// (4 batches x 1 cell per lane; LSTM c-state in registers).
// 4 barriers/step; inputs 4-step batched (vmcnt drain once per 4 steps).
// ---------------------------------------------------------------------------
__global__ __launch_bounds__(512, 1) void main_kernel(
    const float* __restrict__ values, const float* __restrict__ masks,
    const float* __restrict__ labels, const float* __restrict__ is_train,
    const float* __restrict__ b_hr, const float* __restrict__ b_fr,
    const float* __restrict__ b_ih, const float* __restrict__ b_hh,
    const float* __restrict__ W_out, const float* __restrict__ b_out,
    const uint4* __restrict__ whh_ws, const uint4* __restrict__ wih_ws,
    const uint4* __restrict__ whr_ws, const uint4* __restrict__ wfr_ws,
    const float* __restrict__ invms, const float* __restrict__ inv_istr,
    const __half* __restrict__ gh_all, const __half* __restrict__ al_all,
    float* __restrict__ d_out) {
    // ---- LDS ----
    __shared__ __align__(16) __half hdp[BPB][136];     // decayed h (A source), pad 8
    __shared__ __align__(16) __half xcp[BPB][72];      // x_c (A source), pad 8
    __shared__ __align__(16) __half ccp[BPB][72];      // c_c (A source), pad 8
    __shared__ float xs[4][BPB][68], ms[4][BPB][68];   // staged x, m (f32)
    __shared__ __align__(16) __half als[4][BPB][72];   // staged alpha
    __shared__ __align__(16) __half mp16[4][BPB][72];  // staged m (f16, A source)
    __shared__ __align__(16) __half gams[4][BPB][136]; // staged gamma_h(t+1)
    __shared__ float sinv4[4];
    __shared__ float hfin[BPB][128];
    __shared__ float redl[512];
    __shared__ float ylarr[BPB];

    const int tid = threadIdx.x;
    const int w = tid >> 6;          // wave id: owns cells [w*16, w*16+16)
    const int l = tid & 63;
    const int lr = l & 15;           // tile col
    const int lg = l >> 4;           // k-group / row-group
    const int b0 = blockIdx.x * BPB;
    const int fcol = w * 16 + lr;    // imputation f-col (waves 0-3)

    // ---- loop-invariant B-fragments (registers/AGPRs; MFMA reads both) ----
    uint4 whhB[4][4];   // [gate][kfrag]  K=128
    uint4 wicB[4][2];   // c_c half of W_ih, K=64
    uint4 wimB[4][2];   // m half of W_ih, K=64
    float bg4[4];
    #pragma unroll
    for (int g = 0; g < 4; g++) {
        int n = g * 128 + w * 16 + lr;
        #pragma unroll
        for (int q = 0; q < 4; q++) whhB[g][q] = whh_ws[(q * 4 + lg) * 512 + n];
        #pragma unroll
        for (int q = 0; q < 2; q++) {
            wicB[g][q] = wih_ws[(q * 4 + lg) * 512 + n];
            wimB[g][q] = wih_ws[((q + 2) * 4 + lg) * 512 + n];
        }
        bg4[g] = b_ih[n] + b_hh[n];
    }
    uint4 whrB[4], wfrB[2];
    float bhr_r = 0.f, bfr_r = 0.f;
    if (w < 4) {
        #pragma unroll
        for (int q = 0; q < 4; q++) whrB[q] = whr_ws[(q * 4 + lg) * 64 + fcol];
        #pragma unroll
        for (int q = 0; q < 2; q++) wfrB[q] = wfr_ws[(q * 4 + lg) * 64 + fcol];
        bhr_r = b_hr[fcol];
        bfr_r = b_fr[fcol];
    }

    // ---- init LDS state ----
    for (int i = tid; i < BPB * 136; i += 512) ((__half*)hdp)[i] = __float2half(0.f);

    // ---- staging thread mapping ----
    const int bq = tid >> 5;             // batch row 0..15
    const int fq = (tid & 31) * 2;       // f pair
    const int cq4 = (tid & 31) * 4;      // gamma 4-group
    const float* vpb = values + (size_t)(b0 + bq) * NT * NF;
    const float* mpb = masks + (size_t)(b0 + bq) * NT * NF;
    const __half* apb = al_all + (size_t)(b0 + bq) * NT * NF;
    const __half* gpb = gh_all + (size_t)(b0 + bq) * NT * NH;
    float* impb = d_out + 257;

    float2 xr4[4], mr4[4];
    unsigned ar4[4];
    uint2 gr4[4];
    float ir4[4] = {0.f, 0.f, 0.f, 0.f};
    #pragma unroll
    for (int u = 0; u < 4; u++) {
        xr4[u] = *(const float2*)(vpb + (size_t)u * NF + fq);
        mr4[u] = *(const float2*)(mpb + (size_t)u * NF + fq);
        ar4[u] = *(const unsigned*)(apb + (size_t)u * NF + fq);
        gr4[u] = *(const uint2*)(gpb + (size_t)(u + 1) * NH + cq4);
    }
    if (tid == 0) {
        #pragma unroll
        for (int u = 0; u < 4; u++) ir4[u] = invms[u];
    }

    float c4[4] = {0.f, 0.f, 0.f, 0.f};   // LSTM c, 4 batches per lane
    float lloss = 0.f;
    __syncthreads();

    for (int tb = 0; tb < NT; tb += 4) {
        #pragma unroll
        for (int j = 0; j < 4; j++) {
            const int t = tb + j;
            f32x4 accg[4] = {{0.f,0.f,0.f,0.f},{0.f,0.f,0.f,0.f},
                             {0.f,0.f,0.f,0.f},{0.f,0.f,0.f,0.f}};
            f32x4 accx = {0.f, 0.f, 0.f, 0.f};

            // ===== P1: (j==0) commit staged batch + issue next loads;
            //           gates-hh mfma; waves 0-3: x_h mfma =====
            if (j == 0) {
                #pragma unroll
                for (int u = 0; u < 4; u++) {
                    xs[u][bq][fq] = xr4[u].x; xs[u][bq][fq + 1] = xr4[u].y;
                    ms[u][bq][fq] = mr4[u].x; ms[u][bq][fq + 1] = mr4[u].y;
                    *(unsigned*)&als[u][bq][fq] = ar4[u];
                    *(unsigned*)&mp16[u][bq][fq] = pack2(mr4[u].x, mr4[u].y);
                    *(uint2*)&gams[u][bq][cq4] = gr4[u];
                }
                if (tid == 0) {
                    #pragma unroll
                    for (int u = 0; u < 4; u++) sinv4[u] = ir4[u];
                }
                #pragma unroll
                for (int u = 0; u < 4; u++) {
                    int tn = tb + 4 + u; if (tn > NT - 1) tn = NT - 1;
                    int tg = tb + 5 + u; if (tg > NT - 1) tg = NT - 1;
                    xr4[u] = *(const float2*)(vpb + (size_t)tn * NF + fq);
                    mr4[u] = *(const float2*)(mpb + (size_t)tn * NF + fq);
                    ar4[u] = *(const unsigned*)(apb + (size_t)tn * NF + fq);
                    gr4[u] = *(const uint2*)(gpb + (size_t)tg * NH + cq4);
                }
                if (tid == 0) {
                    #pragma unroll
                    for (int u = 0; u < 4; u++) {
                        int tn = tb + 4 + u; if (tn > NT - 1) tn = NT - 1;
                        ir4[u] = invms[tn];
                    }
                }
            }
            #pragma unroll
            for (int q = 0; q < 4; q++) {
                f16x8 a = ldA(&hdp[lr][0], lg, q);
                #pragma unroll
                for (int g = 0; g < 4; g++)
                    accg[g] = __builtin_amdgcn_mfma_f32_16x16x32_f16(a, as_h8(whhB[g][q]), accg[g], 0, 0, 0);
                if (w < 4)
                    accx = __builtin_amdgcn_mfma_f32_16x16x32_f16(a, as_h8(whrB[q]), accx, 0, 0, 0);
            }
            __syncthreads();                       // ---- Bar A

            // ===== P2: waves 0-3: x_c pointwise + write; all: m-gates mfma =====
            float xh4[4], xv4[4], mv4[4];
            if (w < 4) {
                #pragma unroll
                for (int e = 0; e < 4; e++) {
                    int r = lg * 4 + e;
                    float xv = xs[j][r][fcol], mv = ms[j][r][fcol];
                    float xh = accx[e] + bhr_r;
                    float xc = mv * xv + (1.f - mv) * xh;
                    xcp[r][fcol] = __float2half(xc);
                    xh4[e] = xh; xv4[e] = xv; mv4[e] = mv;
                }
            }
            #pragma unroll
            for (int q = 0; q < 2; q++) {
                f16x8 a = ldA(&mp16[j][lr][0], lg, q);
                #pragma unroll
                for (int g = 0; g < 4; g++)
                    accg[g] = __builtin_amdgcn_mfma_f32_16x16x32_f16(a, as_h8(wimB[g][q]), accg[g], 0, 0, 0);
            }
            __syncthreads();                       // ---- Bar B

            // ===== P3: waves 0-3: z_h mfma, ch/cc, loss, imp, write ccp =====
            if (w < 4) {
                f32x4 accz = {0.f, 0.f, 0.f, 0.f};
                #pragma unroll
                for (int q = 0; q < 2; q++) {
                    f16x8 a = ldA(&xcp[lr][0], lg, q);
                    accz = __builtin_amdgcn_mfma_f32_16x16x32_f16(a, as_h8(wfrB[q]), accz, 0, 0, 0);
                }
                float sv = sinv4[j];
                #pragma unroll
                for (int e = 0; e < 4; e++) {
                    int r = lg * 4 + e;
                    float av = __half2float(als[j][r][fcol]);
                    float zh = accz[e] + bfr_r;
                    float ch = av * zh + (1.f - av) * xh4[e];
                    float cc = mv4[e] * xv4[e] + (1.f - mv4[e]) * ch;
                    lloss += (fabsf(xv4[e] - xh4[e]) + fabsf(xv4[e] - zh) +
                              fabsf(xv4[e] - ch)) * mv4[e] * sv;
                    impb[((size_t)(b0 + r) * NT + t) * NF + fcol] = cc;
                    ccp[r][fcol] = __float2half(cc);
                }
            }
            __syncthreads();                       // ---- Bar C

            // ===== P4: cc-gates mfma + LSTM pointwise + hd write =====
            #pragma unroll
            for (int q = 0; q < 2; q++) {
                f16x8 a = ldA(&ccp[lr][0], lg, q);
                #pragma unroll
                for (int g = 0; g < 4; g++)
                    accg[g] = __builtin_amdgcn_mfma_f32_16x16x32_f16(a, as_h8(wicB[g][q]), accg[g], 0, 0, 0);
            }
            {
                const int cell = w * 16 + lr;
                #pragma unroll
                for (int e = 0; e < 4; e++) {
                    int r = lg * 4 + e;
                    float gi = accg[0][e] + bg4[0];
                    float gf = accg[1][e] + bg4[1];
                    float gg = accg[2][e] + bg4[2];
                    float go = accg[3][e] + bg4[3];
                    float cn = sigm(gf) * c4[e] + sigm(gi) * tanh_fast(gg);
                    c4[e] = cn;
                    float hn = sigm(go) * tanh_fast(cn);
                    float gm = __half2float(gams[j][r][cell]);
                    hdp[r][cell] = __float2half(hn * gm);
                    if (t == NT - 1) hfin[r][cell] = hn;
                }
            }
            __syncthreads();                       // ---- Bar D
        }
    }

    // ---- finale: loss reduce, y_h per batch, BCE, atomic ----
    redl[tid] = lloss;
    __syncthreads();
    for (int off = 256; off > 0; off >>= 1) {
        if (tid < off) redl[tid] += redl[tid + off];
        __syncthreads();
    }
    if (tid < BPB) {
        float yp = 0.f;
        for (int c = 0; c < 128; c++) yp += hfin[tid][c] * W_out[c];
        float yh = yp + b_out[0];
        d_out[1 + b0 + tid] = 1.f / (1.f + expf(-yh));
        float lab = labels[b0 + tid], istr = is_train[b0 + tid];
        float maxv = fmaxf(-yh, 0.f);
        float yl = yh - yh * lab + maxv + logf(expf(-maxv) + expf(-yh - maxv));
        ylarr[tid] = yl * istr;
    }
    __syncthreads();
    if (tid == 0) {
        float s = 0.f;
        for (int i = 0; i < BPB; i++) s += ylarr[i];
        atomicAdd(d_out, redl[0] * (1.f / (float)NT) + 0.3f * s * (*inv_istr));
    }
}

// ---------------------------------------------------------------------------
extern "C" void kernel_launch(void* const* d_in, const int* in_sizes, int n_in,
                              void* d_out, int out_size, void* d_ws, size_t ws_size,
                              hipStream_t stream) {
    const float* values = (const float*)d_in[0];
    const float* masks = (const float*)d_in[1];
    const float* deltas = (const float*)d_in[2];
    const float* labels = (const float*)d_in[3];
    const float* is_train = (const float*)d_in[4];
    const float* W_dh = (const float*)d_in[5];
    const float* b_dh = (const float*)d_in[6];
    const float* W_dx = (const float*)d_in[7];
    const float* b_dx = (const float*)d_in[8];
    const float* W_hr = (const float*)d_in[9];
    const float* b_hr = (const float*)d_in[10];
    const float* W_fr = (const float*)d_in[11];
    const float* b_fr = (const float*)d_in[12];
    const float* W_wc = (const float*)d_in[13];
    const float* b_wc = (const float*)d_in[14];
    const float* W_ih = (const float*)d_in[15];
    const float* b_ih = (const float*)d_in[16];
    const float* W_hh = (const float*)d_in[17];
    const float* b_hh = (const float*)d_in[18];
    const float* W_out = (const float*)d_in[19];
    const float* b_out = (const float*)d_in[20];

    char* ws = (char*)d_ws;
    unsigned* wsu = (unsigned*)d_ws;
    const uint4* whh_ws = (const uint4*)(ws + WHH_OFF);
    const uint4* wih_ws = (const uint4*)(ws + WIH_OFF);
    const uint4* whr_ws = (const uint4*)(ws + WHR_OFF);
    const uint4* wfr_ws = (const uint4*)(ws + WFR_OFF);
    float* invms = (float*)(ws + INVMS_OFF);
    float* inv_istr = (float*)(ws + ISTR_OFF);
    __half* gh_all = (__half*)(ws + GH_OFF);
    __half* al_all = (__half*)(ws + AL_OFF);
    float* out_f = (float*)d_out;

    prep_w<<<280, 256, 0, stream>>>(W_hh, W_ih, W_hr, W_fr, wsu);
    prep_msum<<<513, 256, 0, stream>>>(masks, is_train, invms, inv_istr, out_f);
    ga_kernel<<<4096, 256, 0, stream>>>(deltas, masks, W_dh, b_dh, W_dx, b_dx,
                                        W_wc, b_wc, gh_all, al_all);
    main_kernel<<<NBATCH / BPB, 512, 0, stream>>>(values, masks, labels, is_train,
                                                  b_hr, b_fr, b_ih, b_hh, W_out, b_out,
                                                  whh_ws, wih_ws, whr_ws, wfr_ws,
                                                  invms, inv_istr, gh_all, al_all,
                                                  out_f);
}